// Round 14
// baseline (1106.380 us; speedup 1.0000x reference)
//
#include <hip/hip_runtime.h>

// RFNetwork recurrence (in_in_p dead; P = out_in_p):
//   out_t = (W+P) @ x_t ; P = colrenorm(rowrenorm(P + l*outer(out,x)))
// 16x16 grid, block (r,c) owns 64x64 tile of P_tilde in LDS (one-step-lazy
// column factor f: P_true = Pt * diag(f)).
// Protocol = round 13 (passed, 640us) with the drain barriers removed:
//  - A publish: each WAVE stores its 16 (out,R) slots, does its own
//    s_waitcnt vmcnt(0), and sets its per-wave flag fAw[r][c*4+w]. Same
//    ordering primitive as the barrier version (store->ack->atomic flag),
//    minus the block-wide handshake. Consumers poll 16 wave-flags (64B).
//  - B publish: wave 0 only (it owns SLc combine) -> ONE flag fBw[c][r],
//    set after wave-0 vmcnt. Drain-B barrier deleted.
//  - pass1 inputs fully prefetched (X row shared with wrx) -> the A-publish
//    vmcnt ack waits on exactly one outstanding store.
// Safety gating (overwrite of parity slots), semantics preserved from r13:
//  - fAc[c][r]=tg set by tid0 after sync(b) (= block consumed A(t); stronger
//    than r13's drain-A placement). tid<16 poll col-mates' fAc >= tg before
//    sync(c), gating wave0's publish B(t).
//  - fBr[r][c]=tg set with fBw at B publish. tids 64..79 poll row-mates'
//    fBr >= tg before sync(d), gating publish A(t+1) (publishing B(t)
//    implies consumed A(t) a fortiori A(t-1)).
// RULE: cross-block DATA lines single-writer; flags multi-writer only via
// atomic 4B stores. All reduction trees fixed -> bit-deterministic.

typedef float f32x4 __attribute__((ext_vector_type(4)));
typedef float f32x2 __attribute__((ext_vector_type(2)));
typedef unsigned u32x4 __attribute__((ext_vector_type(4)));

#define T_STEPS 128
#define N 1024
#define GR 16
#define GC 16
#define TB 64
#define NT 256
#define LMBDA 0.01f

__global__ __launch_bounds__(NT) void rf2d_kernel(
    const float* __restrict__ X,    // [T][N]
    const float* __restrict__ W,    // [N][N]
    float* __restrict__ OUT,        // [T][N]
    f32x2* __restrict__ OutP,       // [2][GC][N] (out,R) partials
    float* __restrict__ Scol,       // [2][GR][N] colsum partials
    unsigned* __restrict__ fAw,     // [GR][GC*4] per-wave A publish flags
    unsigned* __restrict__ fBw,     // [GC][GR] B publish flags (wave0)
    unsigned* __restrict__ fAc,     // [GC][GR] "consumed A" safety flags
    unsigned* __restrict__ fBr) {   // [GR][GC] B publish flags, row-major
  __shared__ float Pl[TB * TB];     // 16 KB tile, f32x4-chunk XOR swizzle
  __shared__ float f_loc[TB];
  __shared__ float rfl[TB], oll[TB];
  __shared__ float SLc[4][TB];
  __shared__ float SLd[4][TB];
  __shared__ float sxAll[T_STEPS];

  const int tid = threadIdx.x;
  const int b = blockIdx.x;
  const int r = b >> 4, c = b & 15;
  const int grow = r * TB, gcol = c * TB;
  const int r_loc = tid >> 2, q = tid & 3;   // pass1: 4 lanes per row
  const int c_loc = tid & 63, rg = tid >> 6; // wave id / pass2 slice
  const int lane = tid & 63;

  // ---- init ----
  for (int i = tid; i < TB * TB; i += NT) Pl[i] = 0.f;
  if (tid < TB) f_loc[tid] = 1.f;
  {  // sx[t] for all steps (X fixed): 2 threads per row, fixed combine order
    const int rowi = tid >> 1, half = tid & 1;
    const f32x4* Xr = (const f32x4*)(X + (size_t)rowi * N) + half * 128;
    f32x4 acc = {0.f, 0.f, 0.f, 0.f};
    for (int j = 0; j < 128; ++j) acc += Xr[j];
    ((float*)SLc)[tid] = (acc.x + acc.y) + (acc.z + acc.w);
  }
  __syncthreads();
  if (tid < T_STEPS)
    sxAll[tid] = ((float*)SLc)[2 * tid] + ((float*)SLc)[2 * tid + 1];

  f32x4 wr[4];
#pragma unroll
  for (int k = 0; k < 4; ++k)
    wr[k] = *(const f32x4*)(W + (size_t)(grow + r_loc) * N + gcol + 16 * q + 4 * k);

  // prefetch x(0) fragment + W.x partial for t=0
  f32x4 xn[4];
  float wrx = 0.f;
  {
    const f32x4* Xn = (const f32x4*)(X + gcol);
#pragma unroll
    for (int k = 0; k < 4; ++k) {
      xn[k] = Xn[4 * q + k];
      wrx += (wr[k].x * xn[k].x + wr[k].y * xn[k].y) +
             (wr[k].z * xn[k].z + wr[k].w * xn[k].w);
    }
  }
  __syncthreads();

  for (int t = 0; t < T_STEPS; ++t) {
    const int p = t & 1;
    const unsigned tg = t + 1u;

    // ---- pass1: tile partials (LDS + registers only) ----
    float a_out = wrx, a_R = 0.f;
    {
      const f32x4* PlV = (const f32x4*)Pl;
      const f32x4* FV = (const f32x4*)f_loc;
#pragma unroll
      for (int k = 0; k < 4; ++k) {
        const int lc = 4 * q + k;
        f32x4 pv = PlV[r_loc * 16 + (lc ^ (r_loc & 15))];
        f32x4 fv = FV[lc];
        f32x4 pf = pv * fv;
        a_R += (pf.x + pf.y) + (pf.z + pf.w);
        a_out += (pf.x * xn[k].x + pf.y * xn[k].y) +
                 (pf.z * xn[k].z + pf.w * xn[k].w);
      }
    }
    a_out += __shfl_xor(a_out, 1, 64); a_out += __shfl_xor(a_out, 2, 64);
    a_R   += __shfl_xor(a_R, 1, 64);   a_R   += __shfl_xor(a_R, 2, 64);

    // ---- publish A (single-writer span) + PER-WAVE drain + wave flag ----
    if (q == 0) {
      f32x2 v; v.x = a_out; v.y = a_R;
      f32x2* dst = OutP + (size_t)p * GC * N + (size_t)c * N + grow + r_loc;
      asm volatile("global_store_dwordx2 %0, %1, off sc0 sc1"
                   :: "v"(dst), "v"(v) : "memory");
    }
    asm volatile("s_waitcnt vmcnt(0)" ::: "memory");
    __builtin_amdgcn_sched_barrier(0);
    if (lane == 0)
      __hip_atomic_store(&fAw[r * 64 + c * 4 + rg], tg, __ATOMIC_RELAXED,
                         __HIP_MEMORY_SCOPE_AGENT);

    // ---- poll 16 wave-flags of own 4 producers (64B, 4 addrs/wave) ----
    {
      const unsigned* fp = fAw + r * 64 + 16 * q;
      u32x4 a0, a1, a2, a3;
      for (;;) {
        asm volatile("global_load_dwordx4 %0, %4, off sc0 sc1\n\t"
                     "global_load_dwordx4 %1, %5, off sc0 sc1\n\t"
                     "global_load_dwordx4 %2, %6, off sc0 sc1\n\t"
                     "global_load_dwordx4 %3, %7, off sc0 sc1\n\t"
                     "s_waitcnt vmcnt(0)"
                     : "=v"(a0), "=v"(a1), "=v"(a2), "=v"(a3)
                     : "v"(fp), "v"(fp + 4), "v"(fp + 8), "v"(fp + 12)
                     : "memory");
        __builtin_amdgcn_sched_barrier(0);
        bool ok = a0.x >= tg && a0.y >= tg && a0.z >= tg && a0.w >= tg &&
                  a1.x >= tg && a1.y >= tg && a1.z >= tg && a1.w >= tg &&
                  a2.x >= tg && a2.y >= tg && a2.z >= tg && a2.w >= tg &&
                  a3.x >= tg && a3.y >= tg && a3.z >= tg && a3.w >= tg;
        if (ok) break;
        __builtin_amdgcn_s_sleep(1);
      }
    }
    // ---- read own 4 chunks, reduce ----
    {
      f32x2 v0, v1, v2, v3;
      const f32x2* baseA = OutP + (size_t)p * GC * N + grow + r_loc;
      asm volatile("global_load_dwordx2 %0, %4, off sc0 sc1\n\t"
                   "global_load_dwordx2 %1, %5, off sc0 sc1\n\t"
                   "global_load_dwordx2 %2, %6, off sc0 sc1\n\t"
                   "global_load_dwordx2 %3, %7, off sc0 sc1\n\t"
                   "s_waitcnt vmcnt(0)"
                   : "=v"(v0), "=v"(v1), "=v"(v2), "=v"(v3)
                   : "v"(baseA + (size_t)(4 * q + 0) * N),
                     "v"(baseA + (size_t)(4 * q + 1) * N),
                     "v"(baseA + (size_t)(4 * q + 2) * N),
                     "v"(baseA + (size_t)(4 * q + 3) * N)
                   : "memory");
      __builtin_amdgcn_sched_barrier(0);
      float po = (v0.x + v1.x) + (v2.x + v3.x);
      float pR = (v0.y + v1.y) + (v2.y + v3.y);
      po += __shfl_xor(po, 1, 64); po += __shfl_xor(po, 2, 64);
      pR += __shfl_xor(pR, 1, 64); pR += __shfl_xor(pR, 2, 64);
      float ol = LMBDA * po;
      float R1 = pR + ol * sxAll[t];
      float rf = (R1 > 1.f) ? 1.f / R1 : 1.f;  // MAX_POST = 1
      if (q == 0) { rfl[r_loc] = rf; oll[r_loc] = ol; }
      if (c == 0 && q == 0) OUT[(size_t)t * N + grow + r_loc] = po;
    }
    if (t == T_STEPS - 1) break;  // state past last output is dead work
    __syncthreads();  // (b) rfl/oll visible; block consumed A(t)

    if (tid == 0)  // safety: "consumed A(t)" (gates col-mates' publish B(t))
      __hip_atomic_store(&fAc[c * GR + r], tg, __ATOMIC_RELAXED,
                         __HIP_MEMORY_SCOPE_AGENT);

    // ---- pass2 (round-6 association): v = rf*(Pt*f + ol*x) ----
    {
      const float xc = X[(size_t)t * N + gcol + c_loc];
      const float fc = f_loc[c_loc];
      float cacc = 0.f;
#pragma unroll
      for (int rr = 0; rr < 16; ++rr) {
        const int row = rg * 16 + rr;
        const int idx = row * 64 + ((((c_loc >> 2) ^ (row & 15))) << 2) + (c_loc & 3);
        float v = rfl[row] * (Pl[idx] * fc + oll[row] * xc);
        Pl[idx] = v;
        cacc += v;
      }
      SLc[rg][c_loc] = cacc;
    }
    // safety pollA-col (gates publish B(t)); wave-0 lanes, pre-sync(c)
    if (tid < 16) {
      while (__hip_atomic_load(&fAc[c * GR + tid], __ATOMIC_RELAXED,
                               __HIP_MEMORY_SCOPE_AGENT) < tg)
        __builtin_amdgcn_s_sleep(1);
    }
    __syncthreads();  // (c) SLc visible; safety poll done

    // ---- publish B: wave 0 only; per-wave drain; single flag ----
    if (tid < TB) {
      float scol = (SLc[0][tid] + SLc[1][tid]) + (SLc[2][tid] + SLc[3][tid]);
      float* dst = Scol + (size_t)p * GR * N + (size_t)r * N + gcol + tid;
      asm volatile("global_store_dword %0, %1, off sc0 sc1"
                   :: "v"(dst), "v"(scol) : "memory");
      asm volatile("s_waitcnt vmcnt(0)" ::: "memory");
      __builtin_amdgcn_sched_barrier(0);
      if (lane == 0) {
        __hip_atomic_store(&fBw[c * GR + r], tg, __ATOMIC_RELAXED,
                           __HIP_MEMORY_SCOPE_AGENT);
        __hip_atomic_store(&fBr[r * GC + c], tg, __ATOMIC_RELAXED,
                           __HIP_MEMORY_SCOPE_AGENT);
      }
    }

    // ---- hidden under B-wait: prefetch x(t+1) fragment + W.x partial ----
    {
      const f32x4* Xn = (const f32x4*)(X + (size_t)(t + 1) * N + gcol);
      wrx = 0.f;
#pragma unroll
      for (int k = 0; k < 4; ++k) {
        xn[k] = Xn[4 * q + k];
        wrx += (wr[k].x * xn[k].x + wr[k].y * xn[k].y) +
               (wr[k].z * xn[k].z + wr[k].w * xn[k].w);
      }
    }

    // ---- poll own 4 B-producer flags (one dwordx4, uniform per wave) ----
    {
      const unsigned* fp = fBw + c * GR + 4 * rg;
      u32x4 fv;
      for (;;) {
        asm volatile("global_load_dwordx4 %0, %1, off sc0 sc1\n\ts_waitcnt vmcnt(0)"
                     : "=v"(fv) : "v"(fp) : "memory");
        __builtin_amdgcn_sched_barrier(0);
        if (fv.x >= tg && fv.y >= tg && fv.z >= tg && fv.w >= tg) break;
        __builtin_amdgcn_s_sleep(1);
      }
    }
    // ---- read own 4 colsum chunks ----
    {
      float u0, u1, u2, u3;
      const float* baseB = Scol + (size_t)p * GR * N + gcol + c_loc;
      asm volatile("global_load_dword %0, %4, off sc0 sc1\n\t"
                   "global_load_dword %1, %5, off sc0 sc1\n\t"
                   "global_load_dword %2, %6, off sc0 sc1\n\t"
                   "global_load_dword %3, %7, off sc0 sc1\n\t"
                   "s_waitcnt vmcnt(0)"
                   : "=v"(u0), "=v"(u1), "=v"(u2), "=v"(u3)
                   : "v"(baseB + (size_t)(4 * rg + 0) * N),
                     "v"(baseB + (size_t)(4 * rg + 1) * N),
                     "v"(baseB + (size_t)(4 * rg + 2) * N),
                     "v"(baseB + (size_t)(4 * rg + 3) * N)
                   : "memory");
      __builtin_amdgcn_sched_barrier(0);
      SLd[rg][c_loc] = (u0 + u1) + (u2 + u3);
    }
    // safety pollB-row (gates publish A(t+1)); wave-1 lanes, pre-sync(d)
    if (tid >= 64 && tid < 80) {
      while (__hip_atomic_load(&fBr[r * GC + (tid - 64)], __ATOMIC_RELAXED,
                               __HIP_MEMORY_SCOPE_AGENT) < tg)
        __builtin_amdgcn_s_sleep(1);
    }
    __syncthreads();  // (d) SLd visible; safety poll done
    if (tid < TB) {
      float s = (SLd[0][tid] + SLd[1][tid]) + (SLd[2][tid] + SLd[3][tid]);
      f_loc[tid] = (s > 1.f) ? 1.f / s : 1.f;  // MAX_PRE = 1
    }
    __syncthreads();  // (e) f_loc visible
  }
}

extern "C" void kernel_launch(void* const* d_in, const int* in_sizes, int n_in,
                              void* d_out, int out_size, void* d_ws, size_t ws_size,
                              hipStream_t stream) {
  const float* X = (const float*)d_in[0];   // inputs [128][1024]
  const float* W = (const float*)d_in[2];   // out_in_fixed [1024][1024]
  float* OUT = (float*)d_out;               // [128][1024] f32

  char* ws = (char*)d_ws;
  // layout: fAw 4KB | fBw 1KB | fAc 1KB | fBr 1KB | pad->8KB | OutP | Scol
  unsigned* fAw = (unsigned*)ws;
  unsigned* fBw = (unsigned*)(ws + 4096);
  unsigned* fAc = (unsigned*)(ws + 5120);
  unsigned* fBr = (unsigned*)(ws + 6144);
  f32x2* OutP = (f32x2*)(ws + 8192);
  float* Scol = (float*)(ws + 8192 + (size_t)2 * GC * N * sizeof(f32x2));

  // flags zero at every (graph-replayed) launch; monotone within a launch.
  // Data buffers need no clear: every read is flag-gated.
  hipMemsetAsync(ws, 0, 8192, stream);

  hipLaunchKernelGGL(rf2d_kernel, dim3(GR * GC), dim3(NT), 0, stream,
                     X, W, OUT, OutP, Scol, fAw, fBw, fAc, fBr);
}

// Round 16
// 723.171 us; speedup vs baseline: 1.5299x; 1.5299x over previous
//
#include <hip/hip_runtime.h>

// RFNetwork recurrence (in_in_p dead; P = out_in_p):
//   out_t = (W+P) @ x_t ; P = colrenorm(rowrenorm(P + l*outer(out,x)))
// 16x16 grid, block (r,c) owns 64x64 tile of P_tilde in LDS (one-step-lazy
// column factor f: P_true = Pt * diag(f)).
// FINAL (= round 13, passed 640us, absmax 0.5). Session findings baked in:
//  - 2 serial cross-device reductions per step (out/R, then colsum) are
//    algorithmically irreducible: colsum needs rf which needs the out/R
//    reduce. Each costs ~1.7-2us of LLC visibility + flag RTT + read RTT.
//  - Publish->drain-barrier->atomic-flag->1-line-poll->read is the ONLY
//    protocol found that is both deterministic and fast. Per-wave vmcnt
//    self-drain + immediate flag RACES (r15/r12: sc0sc1 store ack can
//    precede global visibility); tagged-data detect==consume either races
//    (multi-writer lines, r11/r12) or congests (scattered polls, r7/r8/r14).
//  - POLL RULE: every spin loop polls exactly ONE cache line per thread.
//  - Cross-block DATA lines single-writer; flags multi-writer only via
//    atomic 4B stores.
//  - pass1 PURE-READ (b128 writeback to swizzled slots caused 4.2M LDS
//    bank conflicts in r9); pass2 association rf*(Pt*f + ol*x) -> absmax 0.5.
// All reduction trees fixed -> bit-deterministic. No data atomics.

typedef float f32x4 __attribute__((ext_vector_type(4)));
typedef float f32x2 __attribute__((ext_vector_type(2)));
typedef unsigned u32x4 __attribute__((ext_vector_type(4)));

#define T_STEPS 128
#define N 1024
#define GR 16
#define GC 16
#define TB 64
#define NT 256
#define LMBDA 0.01f

__global__ __launch_bounds__(NT) void rf2d_kernel(
    const float* __restrict__ X,    // [T][N]
    const float* __restrict__ W,    // [N][N]
    float* __restrict__ OUT,        // [T][N]
    f32x2* __restrict__ OutP,       // [2][GC][N] (out,R) partials
    float* __restrict__ Scol,       // [2][GR][N] colsum partials
    unsigned* __restrict__ fAr,     // [GR][GC] A-publish flags, row-major
    unsigned* __restrict__ fAc,     // [GC][GR] A-publish flags, col-major
    unsigned* __restrict__ fBc,     // [GC][GR] B-publish flags, col-major
    unsigned* __restrict__ fBr) {   // [GR][GC] B-publish flags, row-major
  __shared__ float Pl[TB * TB];     // 16 KB tile, f32x4-chunk XOR swizzle
  __shared__ float f_loc[TB];
  __shared__ float rfl[TB], oll[TB];
  __shared__ float SLc[4][TB];
  __shared__ float SLd[4][TB];
  __shared__ float sxAll[T_STEPS];

  const int tid = threadIdx.x;
  const int b = blockIdx.x;
  const int r = b >> 4, c = b & 15;
  const int grow = r * TB, gcol = c * TB;
  const int r_loc = tid >> 2, q = tid & 3;   // pass1: 4 lanes per row
  const int c_loc = tid & 63, rg = tid >> 6; // pass2: column slice

  // ---- init ----
  for (int i = tid; i < TB * TB; i += NT) Pl[i] = 0.f;
  if (tid < TB) f_loc[tid] = 1.f;
  {  // sx[t] for all steps (X fixed): 2 threads per row, fixed combine order
    const int rowi = tid >> 1, half = tid & 1;
    const f32x4* Xr = (const f32x4*)(X + (size_t)rowi * N) + half * 128;
    f32x4 acc = {0.f, 0.f, 0.f, 0.f};
    for (int j = 0; j < 128; ++j) acc += Xr[j];
    ((float*)SLc)[tid] = (acc.x + acc.y) + (acc.z + acc.w);
  }
  __syncthreads();
  if (tid < T_STEPS)
    sxAll[tid] = ((float*)SLc)[2 * tid] + ((float*)SLc)[2 * tid + 1];

  f32x4 wr[4];
#pragma unroll
  for (int k = 0; k < 4; ++k)
    wr[k] = *(const f32x4*)(W + (size_t)(grow + r_loc) * N + gcol + 16 * q + 4 * k);

  // W.x partial for t=0
  float wrx = 0.f;
  {
    const f32x4* Xn = (const f32x4*)(X + gcol);
#pragma unroll
    for (int k = 0; k < 4; ++k) {
      f32x4 xv = Xn[4 * q + k];
      wrx += (wr[k].x * xv.x + wr[k].y * xv.y) + (wr[k].z * xv.z + wr[k].w * xv.w);
    }
  }
  __syncthreads();

  for (int t = 0; t < T_STEPS; ++t) {
    const int p = t & 1;
    const unsigned tg = t + 1u;

    // ---- pass1: tile partials (PURE LDS reads; no writeback) ----
    float a_out = wrx, a_R = 0.f;
    {
      const f32x4* PlV = (const f32x4*)Pl;
      const f32x4* FV = (const f32x4*)f_loc;
      const f32x4* XV = (const f32x4*)(X + (size_t)t * N + gcol);
#pragma unroll
      for (int k = 0; k < 4; ++k) {
        const int lc = 4 * q + k;
        f32x4 pv = PlV[r_loc * 16 + (lc ^ (r_loc & 15))];
        f32x4 fv = FV[lc];
        f32x4 xv = XV[lc];
        f32x4 pf = pv * fv;
        a_R += (pf.x + pf.y) + (pf.z + pf.w);
        a_out += (pf.x * xv.x + pf.y * xv.y) + (pf.z * xv.z + pf.w * xv.w);
      }
    }
    a_out += __shfl_xor(a_out, 1, 64); a_out += __shfl_xor(a_out, 2, 64);
    a_R   += __shfl_xor(a_R, 1, 64);   a_R   += __shfl_xor(a_R, 2, 64);

    // ---- publish A: (out,R) f32x2 per row (single-writer 512B span) ----
    if (q == 0) {
      f32x2 v; v.x = a_out; v.y = a_R;
      f32x2* dst = OutP + (size_t)p * GC * N + (size_t)c * N + grow + r_loc;
      asm volatile("global_store_dwordx2 %0, %1, off sc0 sc1"
                   :: "v"(dst), "v"(v) : "memory");
    }
    __syncthreads();  // drain-A: all waves' stores at LLC (vmcnt(0) pre-barrier)
    if (tid == 0) {
      __hip_atomic_store(&fAr[r * GC + c], tg, __ATOMIC_RELAXED, __HIP_MEMORY_SCOPE_AGENT);
      __hip_atomic_store(&fAc[c * GR + r], tg, __ATOMIC_RELAXED, __HIP_MEMORY_SCOPE_AGENT);
    }

    // ---- per-thread poll of own 4 producer flags (one dwordx4, 1 line) ----
    {
      const unsigned* fp = fAr + r * GC + 4 * q;
      u32x4 fv;
      for (;;) {
        asm volatile("global_load_dwordx4 %0, %1, off sc0 sc1\n\ts_waitcnt vmcnt(0)"
                     : "=v"(fv) : "v"(fp) : "memory");
        __builtin_amdgcn_sched_barrier(0);
        if (fv.x >= tg && fv.y >= tg && fv.z >= tg && fv.w >= tg) break;
        __builtin_amdgcn_s_sleep(1);
      }
    }
    // ---- read own 4 chunks, reduce ----
    {
      f32x2 v0, v1, v2, v3;
      const f32x2* baseA = OutP + (size_t)p * GC * N + grow + r_loc;
      asm volatile("global_load_dwordx2 %0, %4, off sc0 sc1\n\t"
                   "global_load_dwordx2 %1, %5, off sc0 sc1\n\t"
                   "global_load_dwordx2 %2, %6, off sc0 sc1\n\t"
                   "global_load_dwordx2 %3, %7, off sc0 sc1\n\t"
                   "s_waitcnt vmcnt(0)"
                   : "=v"(v0), "=v"(v1), "=v"(v2), "=v"(v3)
                   : "v"(baseA + (size_t)(4 * q + 0) * N),
                     "v"(baseA + (size_t)(4 * q + 1) * N),
                     "v"(baseA + (size_t)(4 * q + 2) * N),
                     "v"(baseA + (size_t)(4 * q + 3) * N)
                   : "memory");
      __builtin_amdgcn_sched_barrier(0);
      float po = (v0.x + v1.x) + (v2.x + v3.x);
      float pR = (v0.y + v1.y) + (v2.y + v3.y);
      po += __shfl_xor(po, 1, 64); po += __shfl_xor(po, 2, 64);
      pR += __shfl_xor(pR, 1, 64); pR += __shfl_xor(pR, 2, 64);
      float ol = LMBDA * po;
      float R1 = pR + ol * sxAll[t];
      float rf = (R1 > 1.f) ? 1.f / R1 : 1.f;  // MAX_POST = 1
      if (q == 0) { rfl[r_loc] = rf; oll[r_loc] = ol; }
      if (c == 0 && q == 0) OUT[(size_t)t * N + grow + r_loc] = po;
    }
    if (t == T_STEPS - 1) break;  // state past last output is dead work
    __syncthreads();  // (b) rfl/oll visible; block consumed A(t)

    if (tid == 0)  // safety: "consumed A(t)" (gates col-mates' publish B(t))
      __hip_atomic_store(&fAc[c * GR + r], tg, __ATOMIC_RELAXED,
                         __HIP_MEMORY_SCOPE_AGENT);

    // ---- pass2 (round-6 association): v = rf*(Pt*f + ol*x) ----
    {
      const float xc = X[(size_t)t * N + gcol + c_loc];
      const float fc = f_loc[c_loc];
      float cacc = 0.f;
#pragma unroll
      for (int rr = 0; rr < 16; ++rr) {
        const int row = rg * 16 + rr;
        const int idx = row * 64 + ((((c_loc >> 2) ^ (row & 15))) << 2) + (c_loc & 3);
        float v = rfl[row] * (Pl[idx] * fc + oll[row] * xc);
        Pl[idx] = v;
        cacc += v;
      }
      SLc[rg][c_loc] = cacc;
    }
    // safety pollA-col (gates publish B(t)): transitive overwrite proof
    if (tid < 16) {
      while (__hip_atomic_load(&fAc[c * GR + tid], __ATOMIC_RELAXED,
                               __HIP_MEMORY_SCOPE_AGENT) < tg)
        __builtin_amdgcn_s_sleep(1);
    }
    __syncthreads();  // (c) SLc visible; safety poll done

    // ---- publish B: colsum float per column (single-writer 256B span) ----
    if (tid < TB) {
      float scol = (SLc[0][tid] + SLc[1][tid]) + (SLc[2][tid] + SLc[3][tid]);
      float* dst = Scol + (size_t)p * GR * N + (size_t)r * N + gcol + tid;
      asm volatile("global_store_dword %0, %1, off sc0 sc1"
                   :: "v"(dst), "v"(scol) : "memory");
    }
    __syncthreads();  // drain-B
    if (tid == 0) {
      __hip_atomic_store(&fBc[c * GR + r], tg, __ATOMIC_RELAXED, __HIP_MEMORY_SCOPE_AGENT);
      __hip_atomic_store(&fBr[r * GC + c], tg, __ATOMIC_RELAXED, __HIP_MEMORY_SCOPE_AGENT);
    }

    // ---- hidden under B-wait: W.x partial for step t+1 ----
    wrx = 0.f;
    {
      const f32x4* Xn = (const f32x4*)(X + (size_t)(t + 1) * N + gcol);
#pragma unroll
      for (int k = 0; k < 4; ++k) {
        f32x4 xv = Xn[4 * q + k];
        wrx += (wr[k].x * xv.x + wr[k].y * xv.y) + (wr[k].z * xv.z + wr[k].w * xv.w);
      }
    }

    // ---- per-thread poll of own 4 B-producer flags (one dwordx4) ----
    {
      const unsigned* fp = fBc + c * GR + 4 * rg;
      u32x4 fv;
      for (;;) {
        asm volatile("global_load_dwordx4 %0, %1, off sc0 sc1\n\ts_waitcnt vmcnt(0)"
                     : "=v"(fv) : "v"(fp) : "memory");
        __builtin_amdgcn_sched_barrier(0);
        if (fv.x >= tg && fv.y >= tg && fv.z >= tg && fv.w >= tg) break;
        __builtin_amdgcn_s_sleep(1);
      }
    }
    // ---- read own 4 colsum chunks ----
    {
      float u0, u1, u2, u3;
      const float* baseB = Scol + (size_t)p * GR * N + gcol + c_loc;
      asm volatile("global_load_dword %0, %4, off sc0 sc1\n\t"
                   "global_load_dword %1, %5, off sc0 sc1\n\t"
                   "global_load_dword %2, %6, off sc0 sc1\n\t"
                   "global_load_dword %3, %7, off sc0 sc1\n\t"
                   "s_waitcnt vmcnt(0)"
                   : "=v"(u0), "=v"(u1), "=v"(u2), "=v"(u3)
                   : "v"(baseB + (size_t)(4 * rg + 0) * N),
                     "v"(baseB + (size_t)(4 * rg + 1) * N),
                     "v"(baseB + (size_t)(4 * rg + 2) * N),
                     "v"(baseB + (size_t)(4 * rg + 3) * N)
                   : "memory");
      __builtin_amdgcn_sched_barrier(0);
      SLd[rg][c_loc] = (u0 + u1) + (u2 + u3);
    }
    // safety pollB-row (gates publish A(t+1)): done before sync (d)
    if (tid >= 16 && tid < 32) {
      while (__hip_atomic_load(&fBr[r * GC + (tid - 16)], __ATOMIC_RELAXED,
                               __HIP_MEMORY_SCOPE_AGENT) < tg)
        __builtin_amdgcn_s_sleep(1);
    }
    __syncthreads();  // (d) SLd visible; safety poll done
    if (tid < TB) {
      float s = (SLd[0][tid] + SLd[1][tid]) + (SLd[2][tid] + SLd[3][tid]);
      f_loc[tid] = (s > 1.f) ? 1.f / s : 1.f;  // MAX_PRE = 1
    }
    __syncthreads();  // (e) f_loc visible
  }
}

extern "C" void kernel_launch(void* const* d_in, const int* in_sizes, int n_in,
                              void* d_out, int out_size, void* d_ws, size_t ws_size,
                              hipStream_t stream) {
  const float* X = (const float*)d_in[0];   // inputs [128][1024]
  const float* W = (const float*)d_in[2];   // out_in_fixed [1024][1024]
  float* OUT = (float*)d_out;               // [128][1024] f32

  char* ws = (char*)d_ws;
  // layout: fAr|fAc|fBc|fBr (1KB each, memset) | OutP 256KB | Scol 128KB
  unsigned* fAr = (unsigned*)ws;
  unsigned* fAc = (unsigned*)(ws + 1024);
  unsigned* fBc = (unsigned*)(ws + 2048);
  unsigned* fBr = (unsigned*)(ws + 3072);
  f32x2* OutP = (f32x2*)(ws + 4096);
  float* Scol = (float*)(ws + 4096 + (size_t)2 * GC * N * sizeof(f32x2));

  // flags zero at every (graph-replayed) launch; monotone within a launch.
  // Data buffers need no clear: every read is flag-gated.
  hipMemsetAsync(ws, 0, 4096, stream);

  hipLaunchKernelGGL(rf2d_kernel, dim3(GR * GC), dim3(NT), 0, stream,
                     X, W, OUT, OutP, Scol, fAr, fAc, fBc, fBr);
}